// Round 9
// baseline (119.515 us; speedup 1.0000x reference)
//
#include <hip/hip_runtime.h>
#include <hip/hip_fp16.h>
#include <cstdint>

#define VOCAB 50000
#define EMB   300
#define SEQ   80
#define HID   128
#define BATCH 4096

typedef __attribute__((ext_vector_type(8))) _Float16 f16x8;
typedef __attribute__((ext_vector_type(4))) float    f32x4;

static __device__ __forceinline__ float fast_tanh(float xv) {
    const float e = __expf(2.f * xv);
    float r;
    asm("v_rcp_f32 %0, %1" : "=v"(r) : "v"(e + 1.f));
    return fmaf(-2.f, r, 1.f);
}
static __device__ __forceinline__ float f16b2f(unsigned short u) {
    _Float16 h; __builtin_memcpy(&h, &u, 2); return (float)h;
}
static __device__ __forceinline__ unsigned pack2h(float a, float b) {
    _Float16 ha = (_Float16)a, hb = (_Float16)b;
    unsigned short ua, ub;
    __builtin_memcpy(&ua, &ha, 2); __builtin_memcpy(&ub, &hb, 2);
    return (unsigned)ua | ((unsigned)ub << 16);
}

// ---------------------------------------------------------------------------
// k_wprep: fragment tables.
//  W2 (chunks 0..5119):   c=(ks,col,g): W2[c][j] = Wxh[32ks+8g+j][col] (0-pad)
//  W3 (chunks 5120..7167): c2=(ct,ks,lane): W3[c2][j] = Whh[32ks+8g+j][16ct+r16]
// ---------------------------------------------------------------------------
__global__ __launch_bounds__(256) void k_wprep(const float* __restrict__ Wxh,
                                               const float* __restrict__ Whh,
                                               _Float16* __restrict__ W2,
                                               _Float16* __restrict__ W3) {
    const int c = blockIdx.x * 256 + threadIdx.x;
    if (c < 5120) {
        const int ks = c >> 9, rem = c & 511, col = rem >> 2, g = rem & 3;
        f16x8 f;
        #pragma unroll
        for (int j = 0; j < 8; ++j) {
            const int k = 32 * ks + 8 * g + j;
            f[j] = (_Float16)(k < EMB ? Wxh[k * HID + col] : 0.f);
        }
        *reinterpret_cast<f16x8*>(W2 + (size_t)c * 8) = f;
    } else if (c < 7168) {
        const int c2 = c - 5120;
        const int ct = c2 >> 8, ks = (c2 >> 6) & 3, l = c2 & 63;
        const int g = l >> 4, r16 = l & 15;
        f16x8 f;
        #pragma unroll
        for (int j = 0; j < 8; ++j)
            f[j] = (_Float16)Whh[(32 * ks + 8 * g + j) * HID + 16 * ct + r16];
        *reinterpret_cast<f16x8*>(W3 + (size_t)c2 * 8) = f;
    }
}

// ---------------------------------------------------------------------------
// k_ptab: P[v][c] = fp16( emb[v] @ Wxh + bh ). BARRIER-FREE.
// 256 thr / 4 independent waves; wave owns 16 rows x ALL 128 cols:
// emb read exactly once (e-frags in registers), Wxh frags streamed per
// col-tile from L2-resident W2 (prefetched one tile ahead), P stored
// straight from D-layout (uint2 per lane per tile). No LDS, no syncthreads.
// ---------------------------------------------------------------------------
__global__ __launch_bounds__(256, 2) void k_ptab(
    const float*    __restrict__ emb,  // [VOCAB][300]
    const _Float16* __restrict__ W2,   // Wxh frag table
    const float*    __restrict__ bh,   // [128]
    _Float16*       __restrict__ P)    // [VOCAB][128]
{
    const int tid = threadIdx.x, lane = tid & 63, wv = tid >> 6;
    const int r16 = lane & 15, g = lane >> 4;
    const int row = blockIdx.x * 64 + wv * 16 + r16;
    const float* rp = emb + (size_t)(row < VOCAB ? row : VOCAB - 1) * EMB;
    const bool wr = (row < VOCAB);

    // ---- e-fragments (B-layout): ef[ks][j] = e[row][32ks+8g+j] ----
    f16x8 ef[10];
    #pragma unroll
    for (int ks = 0; ks < 9; ++ks) {
        const float4 u0 = *reinterpret_cast<const float4*>(rp + 32 * ks + 8 * g);
        const float4 u1 = *reinterpret_cast<const float4*>(rp + 32 * ks + 8 * g + 4);
        f16x8 f;
        f[0] = (_Float16)u0.x; f[1] = (_Float16)u0.y;
        f[2] = (_Float16)u0.z; f[3] = (_Float16)u0.w;
        f[4] = (_Float16)u1.x; f[5] = (_Float16)u1.y;
        f[6] = (_Float16)u1.z; f[7] = (_Float16)u1.w;
        ef[ks] = f;
    }
    {   // ks = 9: cols 288..299, zero-pad to 320
        f16x8 f;
        #pragma unroll
        for (int j = 0; j < 8; ++j) f[j] = (_Float16)0.f;
        if (g == 0) {
            const float4 u0 = *reinterpret_cast<const float4*>(rp + 288);
            const float4 u1 = *reinterpret_cast<const float4*>(rp + 292);
            f[0] = (_Float16)u0.x; f[1] = (_Float16)u0.y;
            f[2] = (_Float16)u0.z; f[3] = (_Float16)u0.w;
            f[4] = (_Float16)u1.x; f[5] = (_Float16)u1.y;
            f[6] = (_Float16)u1.z; f[7] = (_Float16)u1.w;
        } else if (g == 1) {
            const float4 u0 = *reinterpret_cast<const float4*>(rp + 296);
            f[0] = (_Float16)u0.x; f[1] = (_Float16)u0.y;
            f[2] = (_Float16)u0.z; f[3] = (_Float16)u0.w;
        }
        ef[9] = f;
    }

    // ---- bh fragments (D-layout) ----
    float4 bhf[8];
    #pragma unroll
    for (int ct = 0; ct < 8; ++ct)
        bhf[ct] = *reinterpret_cast<const float4*>(bh + 16 * ct + 4 * g);

    // ---- col-tile loop with W-prefetch (wA/wB alternate) ----
    f16x8 wA[10], wB[10];
    #pragma unroll
    for (int ks = 0; ks < 10; ++ks)
        wA[ks] = *reinterpret_cast<const f16x8*>(
            W2 + ((size_t)ks * 512 + (size_t)r16 * 4 + g) * 8);

    char* const po = (char*)(P + (size_t)(wr ? row : 0) * HID);

    #pragma unroll
    for (int ct = 0; ct < 8; ++ct) {
        if (ct < 7) {
            const int coln = 16 * (ct + 1) + r16;
            #pragma unroll
            for (int ks = 0; ks < 10; ++ks)
                ((ct & 1) ? wA : wB)[ks] = *reinterpret_cast<const f16x8*>(
                    W2 + ((size_t)ks * 512 + (size_t)coln * 4 + g) * 8);
        }
        const f16x8* wc = (ct & 1) ? wB : wA;
        f32x4 a0 = {0.f, 0.f, 0.f, 0.f}, a1 = {0.f, 0.f, 0.f, 0.f};
        #pragma unroll
        for (int ks = 0; ks < 10; ks += 2) {
            a0 = __builtin_amdgcn_mfma_f32_16x16x32_f16(wc[ks],     ef[ks],     a0, 0, 0, 0);
            a1 = __builtin_amdgcn_mfma_f32_16x16x32_f16(wc[ks + 1], ef[ks + 1], a1, 0, 0, 0);
        }
        uint2 o;
        o.x = pack2h(a0[0] + a1[0] + bhf[ct].x, a0[1] + a1[1] + bhf[ct].y);
        o.y = pack2h(a0[2] + a1[2] + bhf[ct].z, a0[3] + a1[3] + bhf[ct].w);
        if (wr) *reinterpret_cast<uint2*>(po + 32 * ct + 8 * g) = o;
    }
}

// ---------------------------------------------------------------------------
// k_rnn: BARRIER-FREE. One wave (64 thr) per block owns 16 batch rows x all
// 128 cols for all 80 steps. Whh in registers (wh[8][4], 128 VGPR).
// Per step: acc init = xp (D-layout uint2 gathers, depth-2 reg pipeline),
// 32 MFMA (8 col-tiles x 4 K-slices, independent chains), 32 tanh,
// intra-wave LDS round-trip (8 ds_write_b64 + 4 ds_read_b128, XOR swizzle)
// to reshape D-layout -> next step's B-frags. No __syncthreads anywhere.
// MFMA 16x16x32 frags: A: lane l = A[l&15][8*(l>>4)+j];
//   B: lane l = B[8*(l>>4)+j][l&15]; D: lane l reg r = D[4*(l>>4)+r][l&15].
// ---------------------------------------------------------------------------
__global__ __launch_bounds__(64, 1) void k_rnn(
    const int*      __restrict__ x,    // [BATCH][SEQ]
    const _Float16* __restrict__ P,    // [VOCAB][128] fp16 (bh folded)
    const _Float16* __restrict__ W3,   // Whh frag table
    const float*    __restrict__ Wd,   // [128]
    const float*    __restrict__ bd,   // [1]
    float*          __restrict__ out)  // [BATCH]
{
    __shared__ __align__(16) unsigned char Hx[16 * 256];  // 4 KB h exchange
    __shared__ int xidx[16 * SEQ];

    const int lane = threadIdx.x;          // 0..63
    const int r16 = lane & 15, g = lane >> 4;
    const int rb = blockIdx.x * 16;

    for (int q = lane; q < 16 * SEQ; q += 64) xidx[q] = x[rb * SEQ + q];

    // ---- Whh fragments: wh[ct][ks], coalesced b128 from W3 ----
    f16x8 wh[8][4];
    #pragma unroll
    for (int ct = 0; ct < 8; ++ct)
        #pragma unroll
        for (int ks = 0; ks < 4; ++ks)
            wh[ct][ks] = *reinterpret_cast<const f16x8*>(
                W3 + ((size_t)(ct * 4 + ks) * 64 + lane) * 8);

    // ---- t-invariant LDS offsets (16B slot XOR r16 swizzle) ----
    int wr_off[8], rd_off[4];
    #pragma unroll
    for (int ct = 0; ct < 8; ++ct)
        wr_off[ct] = r16 * 256 + (((2 * ct + (g >> 1)) ^ r16) & 15) * 16 + (g & 1) * 8;
    #pragma unroll
    for (int ks = 0; ks < 4; ++ks)
        rd_off[ks] = r16 * 256 + (((4 * ks + g) ^ r16) & 15) * 16;

    // ---- h0 = 0; xp depth-2 register pipeline ----
    f16x8 hf[4];
    {
        f16x8 hz;
        #pragma unroll
        for (int j = 0; j < 8; ++j) hz[j] = (_Float16)0.f;
        hf[0] = hz; hf[1] = hz; hf[2] = hz; hf[3] = hz;
    }
    uint2 xc[8], xn[8];
    {
        const int i0 = xidx[r16 * SEQ + 0];
        const int i1 = xidx[r16 * SEQ + 1];
        const char* p0 = (const char*)P + (size_t)i0 * 256 + g * 8;
        const char* p1 = (const char*)P + (size_t)i1 * 256 + g * 8;
        #pragma unroll
        for (int ct = 0; ct < 8; ++ct) {
            xc[ct] = *reinterpret_cast<const uint2*>(p0 + ct * 32);
            xn[ct] = *reinterpret_cast<const uint2*>(p1 + ct * 32);
        }
    }

    f32x4 acc[8], th[8];

#define RNN_STEP(TT, XC, DO_GATHER, DO_EXCH)                                   \
    {                                                                          \
        _Pragma("unroll")                                                      \
        for (int ct = 0; ct < 8; ++ct) {                                       \
            acc[ct][0] = f16b2f((unsigned short)(XC[ct].x & 0xffff));          \
            acc[ct][1] = f16b2f((unsigned short)(XC[ct].x >> 16));             \
            acc[ct][2] = f16b2f((unsigned short)(XC[ct].y & 0xffff));          \
            acc[ct][3] = f16b2f((unsigned short)(XC[ct].y >> 16));             \
        }                                                                      \
        if (DO_GATHER) {  /* refill XC with xp(TT+2); flies under MFMAs */     \
            const int idx2 = xidx[r16 * SEQ + (TT) + 2];                       \
            const char* pp = (const char*)P + (size_t)idx2 * 256 + g * 8;      \
            _Pragma("unroll")                                                  \
            for (int ct = 0; ct < 8; ++ct)                                     \
                XC[ct] = *reinterpret_cast<const uint2*>(pp + ct * 32);        \
        }                                                                      \
        _Pragma("unroll")                                                      \
        for (int ks = 0; ks < 4; ++ks)                                         \
            _Pragma("unroll")                                                  \
            for (int ct = 0; ct < 8; ++ct)                                     \
                acc[ct] = __builtin_amdgcn_mfma_f32_16x16x32_f16(              \
                    wh[ct][ks], hf[ks], acc[ct], 0, 0, 0);                     \
        _Pragma("unroll")                                                      \
        for (int ct = 0; ct < 8; ++ct) {                                       \
            th[ct][0] = fast_tanh(acc[ct][0]);                                 \
            th[ct][1] = fast_tanh(acc[ct][1]);                                 \
            th[ct][2] = fast_tanh(acc[ct][2]);                                 \
            th[ct][3] = fast_tanh(acc[ct][3]);                                 \
        }                                                                      \
        if (DO_EXCH) {                                                         \
            _Pragma("unroll")                                                  \
            for (int ct = 0; ct < 8; ++ct) {                                   \
                uint2 o;                                                       \
                o.x = pack2h(th[ct][0], th[ct][1]);                            \
                o.y = pack2h(th[ct][2], th[ct][3]);                            \
                *reinterpret_cast<uint2*>(Hx + wr_off[ct]) = o;                \
            }                                                                  \
            _Pragma("unroll")                                                  \
            for (int ks = 0; ks < 4; ++ks)                                     \
                hf[ks] = *reinterpret_cast<const f16x8*>(Hx + rd_off[ks]);     \
        }                                                                      \
    }

    #pragma unroll 1
    for (int t = 0; t < SEQ - 3; t += 2) {   // steps 0..77, gathers 2..79
        RNN_STEP(t,     xc, true, true);
        RNN_STEP(t + 1, xn, true, true);
    }
    RNN_STEP(78, xc, false, true);
    RNN_STEP(79, xn, false, false);          // th = h(79) stays in f32 regs
#undef RNN_STEP

    // ---- final dense + sigmoid from f32 h(79) in registers ----
    float part = 0.f;
    #pragma unroll
    for (int ct = 0; ct < 8; ++ct) {
        const float4 wd = *reinterpret_cast<const float4*>(Wd + 16 * ct + 4 * g);
        part += th[ct][0] * wd.x + th[ct][1] * wd.y
              + th[ct][2] * wd.z + th[ct][3] * wd.w;
    }
    part += __shfl_xor(part, 16, 64);
    part += __shfl_xor(part, 32, 64);
    if (lane < 16) out[rb + r16] = 1.f / (1.f + expf(-(part + bd[0])));
}

// ---------------------------------------------------------------------------
extern "C" void kernel_launch(void* const* d_in, const int* in_sizes, int n_in,
                              void* d_out, int out_size, void* d_ws, size_t ws_size,
                              hipStream_t stream)
{
    (void)in_sizes; (void)n_in; (void)out_size; (void)ws_size;
    const int*   x   = (const int*)  d_in[0];
    const float* emb = (const float*)d_in[1];
    const float* Wxh = (const float*)d_in[2];
    const float* Whh = (const float*)d_in[3];
    const float* bh  = (const float*)d_in[4];
    const float* Wd  = (const float*)d_in[5];
    const float* bd  = (const float*)d_in[6];
    float* out = (float*)d_out;

    _Float16* P  = (_Float16*)d_ws;                            // 12.8 MB
    _Float16* W2 = (_Float16*)((char*)d_ws + 12800000);        // 80 KB
    _Float16* W3 = (_Float16*)((char*)d_ws + 12881920);        // 32 KB

    k_wprep<<<28, 256, 0, stream>>>(Wxh, Whh, W2, W3);
    k_ptab<<<(VOCAB + 63) / 64, 256, 0, stream>>>(emb, W2, bh, P);
    k_rnn<<<BATCH / 16, 64, 0, stream>>>(x, P, W3, Wd, bd, out);
}